// Round 2
// baseline (227.414 us; speedup 1.0000x reference)
//
#include <hip/hip_runtime.h>

using u8  = unsigned char;
using u16 = unsigned short;
using u32 = unsigned int;
typedef __attribute__((ext_vector_type(8))) short short8;   // 8 bf16 (MFMA A/B frag)
typedef __attribute__((ext_vector_type(4))) float f32x4;    // MFMA C/D frag

__device__ __forceinline__ u16 f2bf(float f) {
    union { float f; u32 i; } c; c.f = f;
    u32 u = c.i + 0x7FFFu + ((c.i >> 16) & 1u);   // RNE; inputs are finite
    return (u16)(u >> 16);
}

// ---------------------------------------------------------------------------
// Kernel 0: Ap = bf16(x - b_dec) [4096x256], Wb = bf16(W_enc) [8192x256]
// ---------------------------------------------------------------------------
__global__ __launch_bounds__(256) void prep_convert(const float* __restrict__ x,
                                                    const float* __restrict__ b_dec,
                                                    const float* __restrict__ W_enc,
                                                    u16* __restrict__ Ap,
                                                    u16* __restrict__ Wb) {
    int i = blockIdx.x * 256 + threadIdx.x;     // grid covers 3*2^20 exactly
    if (i < 4096 * 256) {
        Ap[i] = f2bf(x[i] - b_dec[i & 255]);
    } else {
        int j = i - 4096 * 256;                 // < 2*2^20
        Wb[j] = f2bf(W_enc[j]);
    }
}

// ---------------------------------------------------------------------------
// Kernel 1: approx pre_acts (u8, scale 32) = relu(Ap @ Wb^T + b_enc)
// M=4096, N=8192, K=256. NT, 128x128 tile, 4 waves of 64x64, 16x16x32 MFMA.
// ---------------------------------------------------------------------------
__global__ __launch_bounds__(256) void encode_gemm(const u16* __restrict__ A,
                                                   const u16* __restrict__ W,
                                                   const float* __restrict__ b_enc,
                                                   u8* __restrict__ pre) {
    const int lane = threadIdx.x & 63;
    const int wave = threadIdx.x >> 6;
    const int wm = wave & 1, wn = wave >> 1;
    const int m0 = blockIdx.y * 128 + wm * 64;
    const int n0 = blockIdx.x * 128 + wn * 64;
    const int r15 = lane & 15;            // m (A) / n (B) within 16-frag
    const int kq  = (lane >> 4) * 8;      // k offset within K=32 chunk

    f32x4 acc[4][4] = {};
    const u16* Abase = A + (size_t)(m0 + r15) * 256 + kq;
    const u16* Wbase = W + (size_t)(n0 + r15) * 256 + kq;

    for (int k0 = 0; k0 < 256; k0 += 32) {
        short8 a[4], b[4];
#pragma unroll
        for (int i = 0; i < 4; i++)
            a[i] = *(const short8*)(Abase + i * 16 * 256 + k0);
#pragma unroll
        for (int j = 0; j < 4; j++)
            b[j] = *(const short8*)(Wbase + j * 16 * 256 + k0);
#pragma unroll
        for (int i = 0; i < 4; i++)
#pragma unroll
            for (int j = 0; j < 4; j++)
                acc[i][j] = __builtin_amdgcn_mfma_f32_16x16x32_bf16(a[i], b[j], acc[i][j], 0, 0, 0);
    }

    // C/D layout: col(n) = lane&15, row(m) = (lane>>4)*4 + reg   [m89-verified]
#pragma unroll
    for (int j = 0; j < 4; j++) {
        int n = n0 + j * 16 + r15;
        float bias = b_enc[n];
#pragma unroll
        for (int i = 0; i < 4; i++) {
            int mrow = m0 + i * 16 + (lane >> 4) * 4;
#pragma unroll
            for (int r = 0; r < 4; r++) {
                float v = acc[i][j][r] + bias;
                v = v > 0.f ? v : 0.f;
                int q = (int)(v * 32.f + 0.5f);
                if (q > 255) q = 255;
                pre[(size_t)(mrow + r) * 8192 + n] = (u8)q;
            }
        }
    }
}

// ---------------------------------------------------------------------------
// Kernel 2: per row — u8 bisection for top-64 screen, exact fp64 refine,
// exact top-32 (val desc, idx asc), fp32 decode. One 256-thread block / row.
// ---------------------------------------------------------------------------
#define CAP 160

__global__ __launch_bounds__(256) void select_decode(const u8* __restrict__ pre,
                                                     const float* __restrict__ x,
                                                     const float* __restrict__ W_enc,
                                                     const float* __restrict__ b_enc,
                                                     const float* __restrict__ W_dec,
                                                     const float* __restrict__ b_dec,
                                                     float* __restrict__ out) {
    const int r    = blockIdx.x;
    const int tid  = threadIdx.x;
    const int lane = tid & 63;
    const int wave = tid >> 6;

    __shared__ int   s_cnt[4];
    __shared__ u32   s_candcnt;
    __shared__ u32   cand_idx[CAP];
    __shared__ float cand_val[CAP];
    __shared__ float sel_val[32];
    __shared__ int   sel_idx[32];

    // --- load this row's 8192 u8 approx values: 32 bytes per thread ---------
    const uint4* prow = (const uint4*)(pre + (size_t)r * 8192);
    uint4 va = prow[2 * tid], vb = prow[2 * tid + 1];
    u32 w[8] = {va.x, va.y, va.z, va.w, vb.x, vb.y, vb.z, vb.w};

    // --- bisection on u8 levels: largest t with count(q >= t) >= 64 ---------
    u32 lo = 0, hi = 256;
    while (hi - lo > 1) {                  // 8 iterations, block-uniform
        u32 mid = (lo + hi) >> 1;
        int c = 0;
#pragma unroll
        for (int q = 0; q < 8; q++) {
            u32 t = w[q];
            c += ((t         & 255u) >= mid);
            c += (((t >> 8)  & 255u) >= mid);
            c += (((t >> 16) & 255u) >= mid);
            c += (((t >> 24) & 255u) >= mid);
        }
#pragma unroll
        for (int off = 32; off; off >>= 1) c += __shfl_down(c, off);
        if (lane == 0) s_cnt[wave] = c;
        __syncthreads();
        int total = s_cnt[0] + s_cnt[1] + s_cnt[2] + s_cnt[3];
        if (total >= 64) lo = mid; else hi = mid;
        __syncthreads();
    }
    u32 thr = lo ? lo : 1u;

    // --- gather candidate indices (q >= thr) ---------------------------------
    if (tid == 0) s_candcnt = 0;
    __syncthreads();
#pragma unroll
    for (int q = 0; q < 8; q++) {
        u32 t = w[q];
        int base = tid * 32 + q * 4;
#pragma unroll
        for (int bn = 0; bn < 4; bn++) {
            if (((t >> (8 * bn)) & 255u) >= thr) {
                u32 p = atomicAdd(&s_candcnt, 1u);
                if (p < CAP) cand_idx[p] = base + bn;
            }
        }
    }
    __syncthreads();
    int m = (int)s_candcnt; if (m > CAP) m = CAP;

    // --- exact refine: fp64 dot(x-b_dec, W_enc[idx]) + b_enc, relu ----------
    float4 sae;
    {
        const float4 xv = *(const float4*)(x + (size_t)r * 256 + lane * 4);
        const float4 bd = *(const float4*)(b_dec + lane * 4);
        sae.x = xv.x - bd.x; sae.y = xv.y - bd.y;
        sae.z = xv.z - bd.z; sae.w = xv.w - bd.w;
    }
    for (int c = wave; c < m; c += 4) {
        int idx = (int)cand_idx[c];
        const float4 wv = *(const float4*)(W_enc + (size_t)idx * 256 + lane * 4);
        double s = (double)sae.x * (double)wv.x + (double)sae.y * (double)wv.y
                 + (double)sae.z * (double)wv.z + (double)sae.w * (double)wv.w;
#pragma unroll
        for (int off = 32; off; off >>= 1) s += __shfl_down(s, off);
        if (lane == 0) {
            float f = (float)(s + (double)b_enc[idx]);
            cand_val[c] = f > 0.f ? f : 0.f;
        }
    }
    __syncthreads();

    // --- exact top-32 by (val desc, idx asc) — matches jax.lax.top_k --------
    if (tid < 32) { sel_val[tid] = 0.f; sel_idx[tid] = 0; }
    __syncthreads();
    if (tid < m) {
        float vi = cand_val[tid];
        int   ii = (int)cand_idx[tid];
        int rank = 0;
        for (int j = 0; j < m; j++) {
            float vj = cand_val[j];
            int   ij = (int)cand_idx[j];
            rank += (vj > vi) || (vj == vi && ij < ii);
        }
        if (rank < 32) { sel_val[rank] = vi; sel_idx[rank] = ii; }
    }
    __syncthreads();

    // --- decode: out[r] = b_dec + sum_k z_k * W_dec[idx_k] (fp32) -----------
    float acc = b_dec[tid];
#pragma unroll 8
    for (int k = 0; k < 32; k++)
        acc += sel_val[k] * W_dec[(size_t)sel_idx[k] * 256 + tid];  // coalesced 1KB row
    out[(size_t)r * 256 + tid] = acc;
}

// ---------------------------------------------------------------------------
extern "C" void kernel_launch(void* const* d_in, const int* in_sizes, int n_in,
                              void* d_out, int out_size, void* d_ws, size_t ws_size,
                              hipStream_t stream) {
    const float* x     = (const float*)d_in[0];   // [4096,256] f32
    const float* W_enc = (const float*)d_in[1];   // [8192,256] f32
    const float* b_enc = (const float*)d_in[2];   // [8192]     f32
    const float* W_dec = (const float*)d_in[3];   // [8192,256] f32
    const float* b_dec = (const float*)d_in[4];   // [256]      f32
    float* out = (float*)d_out;                   // [4096,256] f32

    u8*  pre = (u8*)d_ws;                          // 4096*8192 u8 = 32 MB
    u16* Ap  = (u16*)(pre + (size_t)4096 * 8192);  // +2 MB bf16(x - b_dec)
    u16* Wb  = Ap + (size_t)4096 * 256;            // +4 MB bf16(W_enc)

    prep_convert<<<12288, 256, 0, stream>>>(x, b_dec, W_enc, Ap, Wb);
    encode_gemm<<<dim3(64, 32), 256, 0, stream>>>(Ap, Wb, b_enc, pre);
    select_decode<<<4096, 256, 0, stream>>>(pre, x, W_enc, b_enc, W_dec, b_dec, out);
}

// Round 3
// 211.335 us; speedup vs baseline: 1.0761x; 1.0761x over previous
//
#include <hip/hip_runtime.h>

using u8  = unsigned char;
using u16 = unsigned short;
using u32 = unsigned int;
typedef __attribute__((ext_vector_type(8))) short short8;   // 8 bf16 (MFMA A/B frag)
typedef __attribute__((ext_vector_type(4))) float f32x4;    // MFMA C/D frag

__device__ __forceinline__ u16 f2bf(float f) {
    union { float f; u32 i; } c; c.f = f;
    u32 u = c.i + 0x7FFFu + ((c.i >> 16) & 1u);   // RNE; inputs are finite
    return (u16)(u >> 16);
}

// ---------------------------------------------------------------------------
// Kernel 0: Ap = bf16(x - b_dec) [4096x256], Wb = bf16(W_enc) [8192x256]
// ---------------------------------------------------------------------------
__global__ __launch_bounds__(256) void prep_convert(const float* __restrict__ x,
                                                    const float* __restrict__ b_dec,
                                                    const float* __restrict__ W_enc,
                                                    u16* __restrict__ Ap,
                                                    u16* __restrict__ Wb) {
    int i = blockIdx.x * 256 + threadIdx.x;     // grid covers 3*2^20 exactly
    if (i < 4096 * 256) {
        Ap[i] = f2bf(x[i] - b_dec[i & 255]);
    } else {
        int j = i - 4096 * 256;                 // < 2*2^20
        Wb[j] = f2bf(W_enc[j]);
    }
}

// ---------------------------------------------------------------------------
// Kernel 1: approx pre_acts (u8, scale 32) = relu(Ap @ Wb^T + b_enc)
// M=4096, N=8192, K=256. NT, 128x128 tile, 4 waves of 64x64, 16x16x32 MFMA.
// ---------------------------------------------------------------------------
__global__ __launch_bounds__(256) void encode_gemm(const u16* __restrict__ A,
                                                   const u16* __restrict__ W,
                                                   const float* __restrict__ b_enc,
                                                   u8* __restrict__ pre) {
    const int lane = threadIdx.x & 63;
    const int wave = threadIdx.x >> 6;
    const int wm = wave & 1, wn = wave >> 1;
    const int m0 = blockIdx.y * 128 + wm * 64;
    const int n0 = blockIdx.x * 128 + wn * 64;
    const int r15 = lane & 15;            // m (A) / n (B) within 16-frag
    const int kq  = (lane >> 4) * 8;      // k offset within K=32 chunk

    f32x4 acc[4][4] = {};
    const u16* Abase = A + (size_t)(m0 + r15) * 256 + kq;
    const u16* Wbase = W + (size_t)(n0 + r15) * 256 + kq;

    for (int k0 = 0; k0 < 256; k0 += 32) {
        short8 a[4], b[4];
#pragma unroll
        for (int i = 0; i < 4; i++)
            a[i] = *(const short8*)(Abase + i * 16 * 256 + k0);
#pragma unroll
        for (int j = 0; j < 4; j++)
            b[j] = *(const short8*)(Wbase + j * 16 * 256 + k0);
#pragma unroll
        for (int i = 0; i < 4; i++)
#pragma unroll
            for (int j = 0; j < 4; j++)
                acc[i][j] = __builtin_amdgcn_mfma_f32_16x16x32_bf16(a[i], b[j], acc[i][j], 0, 0, 0);
    }

    // C/D layout: col(n) = lane&15, row(m) = (lane>>4)*4 + reg   [m89-verified]
#pragma unroll
    for (int j = 0; j < 4; j++) {
        int n = n0 + j * 16 + r15;
        float bias = b_enc[n];
#pragma unroll
        for (int i = 0; i < 4; i++) {
            int mrow = m0 + i * 16 + (lane >> 4) * 4;
#pragma unroll
            for (int r = 0; r < 4; r++) {
                float v = acc[i][j][r] + bias;
                v = v > 0.f ? v : 0.f;
                int q = (int)(v * 32.f + 0.5f);
                if (q > 255) q = 255;
                pre[(size_t)(mrow + r) * 8192 + n] = (u8)q;
            }
        }
    }
}

// ---------------------------------------------------------------------------
// Kernel 2: per row — histogram screen (top-64 threshold), rank by u8,
// refine only q >= q32-2 (provably contains true top-32), exact top-32,
// fp32 decode. One 256-thread block per row.
// ---------------------------------------------------------------------------
#define CAP 160

__global__ __launch_bounds__(256) void select_decode(const u8* __restrict__ pre,
                                                     const float* __restrict__ x,
                                                     const float* __restrict__ W_enc,
                                                     const float* __restrict__ b_enc,
                                                     const float* __restrict__ W_dec,
                                                     const float* __restrict__ b_dec,
                                                     float* __restrict__ out) {
    const int r    = blockIdx.x;
    const int tid  = threadIdx.x;
    const int lane = tid & 63;
    const int wave = tid >> 6;
    const int grp  = tid >> 4;     // 16 groups of 16 lanes (for refine)
    const int l16  = tid & 15;

    __shared__ float s_sae[256];
    __shared__ u32   hist[256];
    __shared__ int   wtot[4];
    __shared__ int   s_thr;
    __shared__ int   s_q32;
    __shared__ u32   s_cnt;
    __shared__ int   cand_idx[CAP];
    __shared__ int   cand_q[CAP];
    __shared__ float cand_val[CAP];
    __shared__ float sel_val[32];
    __shared__ int   sel_idx[32];

    // --- load this row's 8192 u8 approx values: 32 bytes per thread ---------
    const uint4* prow = (const uint4*)(pre + (size_t)r * 8192);
    uint4 va = prow[2 * tid], vb = prow[2 * tid + 1];
    u32 w[8] = {va.x, va.y, va.z, va.w, vb.x, vb.y, vb.z, vb.w};

    s_sae[tid] = x[(size_t)r * 256 + tid] - b_dec[tid];
    hist[tid] = 0;
    if (tid == 0) { s_thr = -1; s_q32 = 0; s_cnt = 0; }
    if (tid < 32) { sel_val[tid] = 0.f; sel_idx[tid] = 0; }
    __syncthreads();

    // --- one-pass histogram, bins >= 32 only (value >= 1.0) ------------------
#pragma unroll
    for (int q = 0; q < 8; q++) {
        u32 t = w[q];
#pragma unroll
        for (int bn = 0; bn < 4; bn++) {
            u32 b = (t >> (8 * bn)) & 255u;
            if (b >= 32) atomicAdd(&hist[b], 1u);
        }
    }
    __syncthreads();

    // --- suffix scan: S[b] = count(q >= b); t = max{b : S[b] >= 64} ----------
    int S, c;
    auto scan = [&]() {
        c = (int)hist[tid];
        int s = c;
#pragma unroll
        for (int off = 1; off < 64; off <<= 1) {
            int v = __shfl_down(s, off);
            if (lane + off < 64) s += v;
        }
        if (lane == 0) wtot[wave] = s;
        __syncthreads();
        int hisum = 0;
        for (int ww = wave + 1; ww < 4; ww++) hisum += wtot[ww];
        S = s + hisum;
    };
    scan();
    if (S >= 64 && (S - c) < 64) s_thr = tid;   // unique transition bin
    __syncthreads();
    if (s_thr < 0) {                            // rare: 64th value < 1.0
#pragma unroll
        for (int q = 0; q < 8; q++) {
            u32 t = w[q];
#pragma unroll
            for (int bn = 0; bn < 4; bn++) {
                u32 b = (t >> (8 * bn)) & 255u;
                if (b >= 1 && b < 32) atomicAdd(&hist[b], 1u);
            }
        }
        __syncthreads();
        scan();
        if (S >= 64 && (S - c) < 64) s_thr = tid;
        __syncthreads();
        if (tid == 0 && s_thr < 0) s_thr = 1;   // < 64 positives total
        __syncthreads();
    }
    const int thr = s_thr;

    // --- gather candidates (q >= thr) ----------------------------------------
#pragma unroll
    for (int q = 0; q < 8; q++) {
        u32 t = w[q];
        int base = tid * 32 + q * 4;
#pragma unroll
        for (int bn = 0; bn < 4; bn++) {
            int b = (int)((t >> (8 * bn)) & 255u);
            if (b >= thr) {
                u32 p = atomicAdd(&s_cnt, 1u);
                if (p < CAP) { cand_idx[p] = base + bn; cand_q[p] = b; }
            }
        }
    }
    __syncthreads();
    int m = (int)s_cnt; if (m > CAP) m = CAP;

    // --- q32 = u8 value of rank-31 candidate by (q desc, idx asc) ------------
    if (tid < m) {
        int qi = cand_q[tid], ii = cand_idx[tid], rank = 0;
        for (int j = 0; j < m; j++) {
            int qj = cand_q[j];
            rank += (qj > qi) || (qj == qi && cand_idx[j] < ii);
        }
        if (rank == 31) s_q32 = qi;
    }
    __syncthreads();
    // refine set {q >= q32-2} provably contains the true top-32:
    // 3 u8 levels = 0.094 > 2*(quant 0.0156 + 6-sigma gemm noise 0.010)
    const int qref = s_q32 - 2;    // s_q32==0 when m<=32 -> refine all

    // --- exact refine (fp64): 16-lane group per candidate --------------------
    for (int cc = grp; cc < m; cc += 16) {
        if (cand_q[cc] < qref) continue;        // uniform within group
        int idx = cand_idx[cc];
        const float4* wr = (const float4*)(W_enc + (size_t)idx * 256 + l16 * 16);
        double s = 0.0;
#pragma unroll
        for (int u = 0; u < 4; u++) {
            float4 wv = wr[u];
            const float* sp = &s_sae[l16 * 16 + u * 4];
            s += (double)wv.x * (double)sp[0] + (double)wv.y * (double)sp[1]
               + (double)wv.z * (double)sp[2] + (double)wv.w * (double)sp[3];
        }
#pragma unroll
        for (int off = 8; off; off >>= 1) s += __shfl_down(s, off, 16);
        if (l16 == 0) {
            float f = (float)(s + (double)b_enc[idx]);
            cand_val[cc] = f > 0.f ? f : 0.f;
        }
    }
    __syncthreads();

    // --- exact top-32 among refined by (val desc, idx asc) -------------------
    if (tid < m && cand_q[tid] >= qref) {
        float vi = cand_val[tid];
        int   ii = cand_idx[tid];
        int rank = 0;
        for (int j = 0; j < m; j++) {
            if (cand_q[j] < qref) continue;
            float vj = cand_val[j];
            rank += (vj > vi) || (vj == vi && cand_idx[j] < ii);
        }
        if (rank < 32) { sel_val[rank] = vi; sel_idx[rank] = ii; }
    }
    __syncthreads();

    // --- decode: out[r] = b_dec + sum_k z_k * W_dec[idx_k] (fp32) -----------
    float acc = b_dec[tid];
#pragma unroll 8
    for (int k = 0; k < 32; k++)
        acc += sel_val[k] * W_dec[(size_t)sel_idx[k] * 256 + tid];  // coalesced 1KB row
    out[(size_t)r * 256 + tid] = acc;
}

// ---------------------------------------------------------------------------
extern "C" void kernel_launch(void* const* d_in, const int* in_sizes, int n_in,
                              void* d_out, int out_size, void* d_ws, size_t ws_size,
                              hipStream_t stream) {
    const float* x     = (const float*)d_in[0];   // [4096,256] f32
    const float* W_enc = (const float*)d_in[1];   // [8192,256] f32
    const float* b_enc = (const float*)d_in[2];   // [8192]     f32
    const float* W_dec = (const float*)d_in[3];   // [8192,256] f32
    const float* b_dec = (const float*)d_in[4];   // [256]      f32
    float* out = (float*)d_out;                   // [4096,256] f32

    u8*  pre = (u8*)d_ws;                          // 4096*8192 u8 = 32 MB
    u16* Ap  = (u16*)(pre + (size_t)4096 * 8192);  // +2 MB bf16(x - b_dec)
    u16* Wb  = Ap + (size_t)4096 * 256;            // +4 MB bf16(W_enc)

    prep_convert<<<12288, 256, 0, stream>>>(x, b_dec, W_enc, Ap, Wb);
    encode_gemm<<<dim3(64, 32), 256, 0, stream>>>(Ap, Wb, b_enc, pre);
    select_decode<<<4096, 256, 0, stream>>>(pre, x, W_enc, b_enc, W_dec, b_dec, out);
}